// Round 2
// baseline (504.804 us; speedup 1.0000x reference)
//
#include <hip/hip_runtime.h>

#define NW 64
#define ITERS 10

__global__ __launch_bounds__(256) void damed_median_kernel(
    const float* __restrict__ y, float* __restrict__ out, int D) {
  int d = blockIdx.x * blockDim.x + threadIdx.x;
  if (d >= D) return;

  // Load all 64 worker values for this coordinate into registers.
  // Layout y[w][d]: stride-D across w, coalesced across lanes in d.
  float v[NW];
  float xl = 3.4e38f, xg = -3.4e38f, sum = 0.f;
#pragma unroll
  for (int w = 0; w < NW; ++w) {
    float t = y[(size_t)w * (size_t)D + (size_t)d];
    v[w] = t;
    xl = fminf(xl, t);
    xg = fmaxf(xg, t);
    sum += t;
  }

  // Start from the mean (close to the smooth median), clamped into bracket.
  float x = sum * (1.0f / NW);
  x = fminf(fmaxf(x, xl), xg);

  // Abramowitz-Stegun 7.1.25 erf: erf(a) = 1 - (a1 k + a2 k^2 + a3 k^3) e^{-a^2},
  // k = 1/(1+p a), |err| <= 2.5e-5. exp(-t^2) doubles as the Newton derivative:
  // fm'(x) = -(2/sqrt(pi)) * sum exp(-(y_i - x)^2), so fd costs one extra add.
  const float P = 0.47047f, A1 = 0.3480242f, A2 = -0.0958798f, A3 = 0.7478556f;
  const float C = 1.12837916709551257f;  // 2/sqrt(pi)

  for (int it = 0; it < ITERS; ++it) {
    float fm = 0.f, fd = 0.f;
#pragma unroll
    for (int w = 0; w < NW; ++w) {
      float t = v[w] - x;
      float a = fabsf(t);
      float k = __builtin_amdgcn_rcpf(fmaf(P, a, 1.0f));
      float e = __expf(-t * t);
      float poly = k * fmaf(k, fmaf(k, A3, A2), A1);
      float er = fmaf(-poly, e, 1.0f);   // erf(|t|)
      er = copysignf(er, t);
      fm += er;
      fd += e;
    }
    // Maintain the bracket by sign of fm (fm is decreasing in x).
    if (fm > 0.f) xl = x; else xg = x;
    // Safeguarded Newton. NON-STRICT bracket test: at convergence the step
    // underflows (xn == x == one bracket end); accepting it makes remaining
    // iterations no-ops at the root. Strict (>,<) here bounced a CONVERGED
    // iterate to the bracket midpoint -- the round-1 absmax=1.39 bug.
    // NaN/inf steps (fd->0) fail the comparison -> bisection fallback.
    float xn = x + fm / (C * fd);
    x = (xn >= xl && xn <= xg) ? xn : 0.5f * (xl + xg);
  }
  out[d] = x;
}

extern "C" void kernel_launch(void* const* d_in, const int* in_sizes, int n_in,
                              void* d_out, int out_size, void* d_ws, size_t ws_size,
                              hipStream_t stream) {
  const float* y = (const float*)d_in[0];
  float* out = (float*)d_out;
  const int D = out_size;  // 2^21 coordinates
  const int threads = 256;
  const int blocks = (D + threads - 1) / threads;
  damed_median_kernel<<<blocks, threads, 0, stream>>>(y, out, D);
}

// Round 3
// 169.123 us; speedup vs baseline: 2.9848x; 2.9848x over previous
//
#include <hip/hip_runtime.h>

#define NW 64
#define ITERS 10

// __launch_bounds__(256, 4): 4 blocks/CU target -> VGPR cap ~128. The default
// (no waves arg) made the allocator squeeze to 52 VGPRs, spilling v[64] to
// scratch (~640 extra scratch loads/thread per full run) -- the round-2
// instruction-count gap. v[64]+state ~= 90 VGPR fits under 128.
__global__ __launch_bounds__(256, 4) void damed_median_kernel(
    const float* __restrict__ y, float* __restrict__ out, int D) {
  int d = blockIdx.x * blockDim.x + threadIdx.x;
  if (d >= D) return;

  // All 64 worker values for this coordinate live in registers.
  // y[w][d]: stride-D across w, coalesced across lanes in d.
  float v[NW];
  float xl = 3.4e38f, xg = -3.4e38f, sum = 0.f;
#pragma unroll
  for (int w = 0; w < NW; ++w) {
    float t = y[(size_t)w * (size_t)D + (size_t)d];
    v[w] = t;
    xl = fminf(xl, t);
    xg = fmaxf(xg, t);
    sum += t;
  }

  // Start from the mean (close to the smooth median), clamped into bracket.
  float x = sum * (1.0f / NW);
  x = fminf(fmaxf(x, xl), xg);

  // A&S 7.1.25 erf: erf(a) = 1 - (a1 k + a2 k^2 + a3 k^3) e^{-a^2},
  // k = 1/(1+p a), |err| <= 2.5e-5. exp(-t^2) doubles as the Newton
  // derivative: fm'(x) = -(2/sqrt(pi)) * sum exp(-(y_i - x)^2).
  const float P = 0.47047f, A1 = 0.3480242f, A2 = -0.0958798f, A3 = 0.7478556f;
  const float C = 1.12837916709551257f;  // 2/sqrt(pi)

#pragma unroll 1  // keep the 64-worker body at 1 copy in I-cache; break below
  for (int it = 0; it < ITERS; ++it) {
    // 2-way split accumulators: break the 64-deep dependent add chains
    // (only ~4 waves/SIMD resident; 4-cyc add latency not fully hidden).
    float fm0 = 0.f, fm1 = 0.f, fd0 = 0.f, fd1 = 0.f;
#pragma unroll
    for (int w = 0; w < NW; w += 2) {
      float ta = v[w] - x;
      float tb = v[w + 1] - x;
      float ka = __builtin_amdgcn_rcpf(fmaf(P, fabsf(ta), 1.0f));
      float kb = __builtin_amdgcn_rcpf(fmaf(P, fabsf(tb), 1.0f));
      float ea = __expf(-ta * ta);
      float eb = __expf(-tb * tb);
      float pa = ka * fmaf(ka, fmaf(ka, A3, A2), A1);
      float pb = kb * fmaf(kb, fmaf(kb, A3, A2), A1);
      float era = copysignf(fmaf(-pa, ea, 1.0f), ta);
      float erb = copysignf(fmaf(-pb, eb, 1.0f), tb);
      fm0 += era; fd0 += ea;
      fm1 += erb; fd1 += eb;
    }
    float fm = fm0 + fm1, fd = fd0 + fd1;

    // Maintain the bracket by sign of fm (fm is decreasing in x).
    if (fm > 0.f) xl = x; else xg = x;
    // Safeguarded Newton, NON-STRICT bracket test (round-1 lesson: at
    // convergence xn == x == a bracket end; strict test bounced it to the
    // midpoint). NaN/inf (fd->0) fails the test -> bisection fallback.
    float xn = x + fm / (C * fd);
    float xnew = (xn >= xl && xn <= xg) ? xn : 0.5f * (xl + xg);
    float step = fabsf(xnew - x);
    x = xnew;
    // Wave-uniform early exit: typical coords converge (step==0) by iter
    // 4-5; rare bisection-fallback coords keep the full ITERS safety net.
    // Deterministic for fixed input -> graph-replay safe.
    if (__all(step <= 1e-6f)) break;
  }
  out[d] = x;
}

extern "C" void kernel_launch(void* const* d_in, const int* in_sizes, int n_in,
                              void* d_out, int out_size, void* d_ws, size_t ws_size,
                              hipStream_t stream) {
  const float* y = (const float*)d_in[0];
  float* out = (float*)d_out;
  const int D = out_size;  // 2^21 coordinates
  const int threads = 256;
  const int blocks = (D + threads - 1) / threads;
  damed_median_kernel<<<blocks, threads, 0, stream>>>(y, out, D);
}

// Round 4
// 156.470 us; speedup vs baseline: 3.2262x; 1.0809x over previous
//
#include <hip/hip_runtime.h>

typedef float v2f __attribute__((ext_vector_type(2)));

#define NW 64
#define NP 32          // worker pairs
#define ITERS 10
#define EXIT_TOL 1e-3f // Newton residual after a step s is ~0.5 s^2 (~5e-7);
                       // bisection-fallback coords exit with <=1e-3 extra err.

__global__ __launch_bounds__(256, 4) void damed_median_kernel(
    const float* __restrict__ y, float* __restrict__ out, int D) {
  int d = blockIdx.x * blockDim.x + threadIdx.x;
  if (d >= D) return;

  // 64 worker values, held as 32 register pairs (natural VOP3P operands).
  v2f v[NP];
  float xl = 3.4e38f, xg = -3.4e38f;
  v2f sum2 = {0.f, 0.f};
#pragma unroll
  for (int p = 0; p < NP; ++p) {
    float t0 = y[(size_t)(2 * p) * (size_t)D + (size_t)d];
    float t1 = y[(size_t)(2 * p + 1) * (size_t)D + (size_t)d];
    v2f t = {t0, t1};
    v[p] = t;
    xl = fminf(xl, fminf(t0, t1));
    xg = fmaxf(xg, fmaxf(t0, t1));
    sum2 += t;
  }
  float x = (sum2.x + sum2.y) * (1.0f / NW);
  x = fminf(fmaxf(x, xl), xg);

  // A&S 7.1.25: erf(a) = 1 - (a1 k + a2 k^2 + a3 k^3) e^{-a^2}, k = 1/(1+pa),
  // |err| <= 2.5e-5. e^{-t^2} doubles as the Newton derivative term:
  // fm'(x) = -(2/sqrt(pi)) * sum e^{-(y_i-x)^2}.
  const float P = 0.47047f, A1c = 0.3480242f, A2c = -0.0958798f, A3c = 0.7478556f;
  const float C = 1.12837916709551257f;     // 2/sqrt(pi)
  const float NL2E = -1.44269504088896341f; // -log2(e): e^{-q} = 2^{q*NL2E}
  const v2f one2 = {1.f, 1.f};
  const v2f P2 = {P, P}, A22 = {A2c, A2c}, A12 = {A1c, A1c};
  const v2f A32 = {A3c, A3c}, NL2E2 = {NL2E, NL2E};

#pragma unroll 1  // one copy of the 64-worker body in I-cache
  for (int it = 0; it < ITERS; ++it) {
    // 2x pk accumulators = 4-way effective chain split.
    v2f fmA = {0.f, 0.f}, fmB = {0.f, 0.f}, fdA = {0.f, 0.f}, fdB = {0.f, 0.f};
    v2f nx2 = {-x, -x};
#pragma unroll
    for (int p = 0; p < NP; p += 2) {
      // --- pair A ---
      v2f tA = v[p] + nx2;                                   // pk_add
      v2f aA; aA.x = __builtin_fabsf(tA.x); aA.y = __builtin_fabsf(tA.y);
      v2f hA = __builtin_elementwise_fma(P2, aA, one2);      // pk_fma
      v2f kA; kA.x = __builtin_amdgcn_rcpf(hA.x); kA.y = __builtin_amdgcn_rcpf(hA.y);
      v2f qA = tA * tA;                                      // pk_mul
      v2f mA = qA * NL2E2;                                   // pk_mul
      v2f eA; eA.x = __builtin_amdgcn_exp2f(mA.x); eA.y = __builtin_amdgcn_exp2f(mA.y);
      v2f pA = __builtin_elementwise_fma(kA, A32, A22);
      pA = __builtin_elementwise_fma(kA, pA, A12);
      pA = kA * pA;                                          // 2 pk_fma + pk_mul
      v2f erA = __builtin_elementwise_fma(-pA, eA, one2);    // pk_fma (neg mod)
      erA.x = __builtin_copysignf(erA.x, tA.x);
      erA.y = __builtin_copysignf(erA.y, tA.y);              // 2x v_bfi
      fmA += erA; fdA += eA;                                 // 2 pk_add
      // --- pair B ---
      v2f tB = v[p + 1] + nx2;
      v2f aB; aB.x = __builtin_fabsf(tB.x); aB.y = __builtin_fabsf(tB.y);
      v2f hB = __builtin_elementwise_fma(P2, aB, one2);
      v2f kB; kB.x = __builtin_amdgcn_rcpf(hB.x); kB.y = __builtin_amdgcn_rcpf(hB.y);
      v2f qB = tB * tB;
      v2f mB = qB * NL2E2;
      v2f eB; eB.x = __builtin_amdgcn_exp2f(mB.x); eB.y = __builtin_amdgcn_exp2f(mB.y);
      v2f pB = __builtin_elementwise_fma(kB, A32, A22);
      pB = __builtin_elementwise_fma(kB, pB, A12);
      pB = kB * pB;
      v2f erB = __builtin_elementwise_fma(-pB, eB, one2);
      erB.x = __builtin_copysignf(erB.x, tB.x);
      erB.y = __builtin_copysignf(erB.y, tB.y);
      fmB += erB; fdB += eB;
    }
    v2f fm2 = fmA + fmB, fd2 = fdA + fdB;
    float fm = fm2.x + fm2.y, fd = fd2.x + fd2.y;

    // Bracket update by sign of fm (fm decreasing in x).
    if (fm > 0.f) xl = x; else xg = x;
    // Safeguarded Newton, NON-STRICT bracket test (round-1 lesson: at
    // convergence xn == x == a bracket end). NaN/inf (fd->0) fails -> bisect.
    float xn = x + fm / (C * fd);
    float xnew = (xn >= xl && xn <= xg) ? xn : 0.5f * (xl + xg);
    float step = __builtin_fabsf(xnew - x);
    x = xnew;
    // Wave-uniform early exit; deterministic for fixed input.
    if (__all(step <= EXIT_TOL)) break;
  }
  out[d] = x;
}

extern "C" void kernel_launch(void* const* d_in, const int* in_sizes, int n_in,
                              void* d_out, int out_size, void* d_ws, size_t ws_size,
                              hipStream_t stream) {
  const float* y = (const float*)d_in[0];
  float* out = (float*)d_out;
  const int D = out_size;  // 2^21 coordinates
  const int threads = 256;
  const int blocks = (D + threads - 1) / threads;
  damed_median_kernel<<<blocks, threads, 0, stream>>>(y, out, D);
}

// Round 5
// 139.981 us; speedup vs baseline: 3.6062x; 1.1178x over previous
//
#include <hip/hip_runtime.h>

typedef float v2f __attribute__((ext_vector_type(2)));

#define NW 64
#define NP 32           // worker pairs
#define MAX_EVALS 12
#define FREEZE_TOL 1e-3f

// __launch_bounds__(256,4): VGPR cap ~128 -- without the waves hint the
// allocator squeezed to 52 VGPRs and spilled v[] to scratch (round-2 bug).
__global__ __launch_bounds__(256, 4) void damed_median_kernel(
    const float* __restrict__ y, float* __restrict__ out, int D) {
  int d = blockIdx.x * blockDim.x + threadIdx.x;
  if (d >= D) return;

  // 64 worker values as 32 register pairs (VOP3P operands).
  // y[w][d]: stride-D across w, coalesced across lanes in d.
  v2f v[NP];
  float xl = 3.4e38f, xg = -3.4e38f;
  v2f sum2 = {0.f, 0.f};
#pragma unroll
  for (int p = 0; p < NP; ++p) {
    float t0 = y[(size_t)(2 * p) * (size_t)D + (size_t)d];
    float t1 = y[(size_t)(2 * p + 1) * (size_t)D + (size_t)d];
    v2f t = {t0, t1};
    v[p] = t;
    xl = fminf(xl, fminf(t0, t1));
    xg = fmaxf(xg, fmaxf(t0, t1));
    sum2 += t;
  }
  float x = (sum2.x + sum2.y) * (1.0f / NW);
  x = fminf(fmaxf(x, xl), xg);

  // A&S 7.1.27: erf(a) = 1 - (1 + b1 a + b2 a^2 + b3 a^3 + b4 a^4)^-4,
  // |err| <= 5e-4, NO exp needed (rcp + 2 squarings). Verified: erf(1)->
  // 0.842693 (true 0.842701), erf(2)->0.994866 (true 0.995322).
  const float B1 = 0.278393f, B2 = 0.230389f, B3 = 0.000972f, B4 = 0.078108f;
  const v2f one2 = {1.f, 1.f};
  const v2f Bv1 = {B1, B1}, Bv2 = {B2, B2}, Bv3 = {B3, B3}, Bv4 = {B4, B4};

  // fm(xc) = sum_w erf(v_w - xc); packed, 2x2-way split accumulator chains.
  auto evalF = [&](float xc) -> float {
    v2f fmA = {0.f, 0.f}, fmB = {0.f, 0.f};
    v2f nx = {-xc, -xc};
#pragma unroll
    for (int p = 0; p < NP; p += 2) {
      v2f tA = v[p] + nx;
      v2f tB = v[p + 1] + nx;
      v2f aA, aB;
      aA.x = __builtin_fabsf(tA.x); aA.y = __builtin_fabsf(tA.y);
      aB.x = __builtin_fabsf(tB.x); aB.y = __builtin_fabsf(tB.y);
      v2f pA = __builtin_elementwise_fma(aA, Bv4, Bv3);
      v2f pB = __builtin_elementwise_fma(aB, Bv4, Bv3);
      pA = __builtin_elementwise_fma(aA, pA, Bv2);
      pB = __builtin_elementwise_fma(aB, pB, Bv2);
      pA = __builtin_elementwise_fma(aA, pA, Bv1);
      pB = __builtin_elementwise_fma(aB, pB, Bv1);
      pA = __builtin_elementwise_fma(aA, pA, one2);
      pB = __builtin_elementwise_fma(aB, pB, one2);
      v2f rA, rB;
      rA.x = __builtin_amdgcn_rcpf(pA.x); rA.y = __builtin_amdgcn_rcpf(pA.y);
      rB.x = __builtin_amdgcn_rcpf(pB.x); rB.y = __builtin_amdgcn_rcpf(pB.y);
      rA = rA * rA; rB = rB * rB;   // ^-2
      rA = rA * rA; rB = rB * rB;   // ^-4
      v2f eA = one2 - rA;
      v2f eB = one2 - rB;
      eA.x = __builtin_copysignf(eA.x, tA.x); eA.y = __builtin_copysignf(eA.y, tA.y);
      eB.x = __builtin_copysignf(eB.x, tB.x); eB.y = __builtin_copysignf(eB.y, tB.y);
      fmA += eA;
      fmB += eB;
    }
    v2f s = fmA + fmB;
    return s.x + s.y;
  };

  // --- eval 1 at x0 = clamped mean; first step via analytic expected slope:
  // f'(x) = -C * sum e^{-(y-x)^2}; E[sum e] = 64/sqrt(3) => slope ~= -41.68.
  float fm = evalF(x);
  if (fm > 0.f) xl = x; else xg = x;  // f decreasing: fm>0 => root above x
  float xprev = x, fmprev = fm;
  float xn0 = x + fm * (1.0f / 41.68f);
  xn0 = fminf(fmaxf(xn0, xl), xg);
  float step = __builtin_fabsf(xn0 - x);
  bool frozen = (step <= FREEZE_TOL);  // fm==0 -> done immediately
  x = xn0;

  // --- guarded secant; per-lane freeze prevents the converged-lane
  // denom->0 -> NaN -> midpoint bounce (round-1 lesson, secant edition).
#pragma unroll 1
  for (int e = 1; e < MAX_EVALS; ++e) {
    float fmc = evalF(x);
    if (fmc > 0.f) xl = x; else xg = x;
    float denom = fmprev - fmc;  // = -(f_n - f_{n-1})
    float xn = x + fmc * (x - xprev) / denom;  // secant step
    bool ok = (xn >= xl) && (xn <= xg);        // NaN fails -> bisect
    float cand = ok ? xn : 0.5f * (xl + xg);
    float st = __builtin_fabsf(cand - x);
    float xnew = frozen ? x : cand;            // frozen lanes do not move
    xprev = frozen ? xprev : x;
    fmprev = frozen ? fmprev : fmc;
    frozen = frozen || (st <= FREEZE_TOL);
    x = xnew;
    if (__all(frozen)) break;  // wave-uniform exit; deterministic
  }
  out[d] = x;
}

extern "C" void kernel_launch(void* const* d_in, const int* in_sizes, int n_in,
                              void* d_out, int out_size, void* d_ws, size_t ws_size,
                              hipStream_t stream) {
  const float* y = (const float*)d_in[0];
  float* out = (float*)d_out;
  const int D = out_size;  // 2^21 coordinates
  const int threads = 256;
  const int blocks = (D + threads - 1) / threads;
  damed_median_kernel<<<blocks, threads, 0, stream>>>(y, out, D);
}